// Round 4
// baseline (105080.920 us; speedup 1.0000x reference)
//
#include <hip/hip_runtime.h>
#include <hip/hip_cooperative_groups.h>

namespace cg = cooperative_groups;

#define BB 128
#define TT 512
#define DD 256
#define HH 512

#define WP0_FLOATS (2048 * 768)   // L0 packed weights
#define WP1_FLOATS (2048 * 1024)  // L1 packed weights

__device__ __forceinline__ float sig_(float x) { return 1.0f / (1.0f + __expf(-x)); }

// ---------------- projection GEMM: xp = x @ proj_w.T + proj_b ----------------
__global__ __launch_bounds__(256) void proj_kernel(const float* __restrict__ x,
                                                   const float* __restrict__ pw,
                                                   const float* __restrict__ pb,
                                                   float* __restrict__ xp) {
  __shared__ float At[64 * 68];
  __shared__ float Bt[64 * 68];
  const int bm = blockIdx.x >> 2;
  const int bn = blockIdx.x & 3;
  const int tid = threadIdx.x;
  const int rg = tid >> 4;
  const int cgi = tid & 15;
  const int m0 = bm * 64, n0 = bn * 64;
  float acc[4][4] = {};
  for (int kt = 0; kt < 4; ++kt) {
    const int k0 = kt * 64;
    {
      const int r = tid >> 2, q = tid & 3;
      const float4* src = (const float4*)(x + (size_t)(m0 + r) * DD + k0 + q * 16);
      float4* dst = (float4*)&At[r * 68 + q * 16];
#pragma unroll
      for (int j = 0; j < 4; ++j) dst[j] = src[j];
    }
    {
      const int n = tid & 63, kg = tid >> 6;
      const float4* src = (const float4*)(pw + (size_t)(n0 + n) * DD + k0 + kg * 16);
#pragma unroll
      for (int j = 0; j < 4; ++j) {
        float4 v = src[j];
        const int kk = kg * 16 + j * 4;
        Bt[(kk + 0) * 68 + n] = v.x;
        Bt[(kk + 1) * 68 + n] = v.y;
        Bt[(kk + 2) * 68 + n] = v.z;
        Bt[(kk + 3) * 68 + n] = v.w;
      }
    }
    __syncthreads();
#pragma unroll
    for (int k4 = 0; k4 < 64; k4 += 4) {
      float4 a[4], b[4];
#pragma unroll
      for (int j = 0; j < 4; ++j) a[j] = *(const float4*)&At[(rg * 4 + j) * 68 + k4];
#pragma unroll
      for (int j = 0; j < 4; ++j) b[j] = *(const float4*)&Bt[(k4 + j) * 68 + cgi * 4];
#pragma unroll
      for (int jr = 0; jr < 4; ++jr) {
#pragma unroll
        for (int q = 0; q < 4; ++q) {
          const float av = q == 0 ? a[jr].x : q == 1 ? a[jr].y : q == 2 ? a[jr].z : a[jr].w;
          acc[jr][0] = fmaf(av, b[q].x, acc[jr][0]);
          acc[jr][1] = fmaf(av, b[q].y, acc[jr][1]);
          acc[jr][2] = fmaf(av, b[q].z, acc[jr][2]);
          acc[jr][3] = fmaf(av, b[q].w, acc[jr][3]);
        }
      }
    }
    __syncthreads();
  }
  const float4 bias = *(const float4*)&pb[n0 + cgi * 4];
#pragma unroll
  for (int jr = 0; jr < 4; ++jr) {
    float4 o;
    o.x = acc[jr][0] + bias.x;
    o.y = acc[jr][1] + bias.y;
    o.z = acc[jr][2] + bias.z;
    o.w = acc[jr][3] + bias.w;
    *(float4*)&xp[(size_t)(m0 + rg * 4 + jr) * DD + n0 + cgi * 4] = o;
  }
}

// ---------------- weight pack (layout validated in round 2) ----------------
// Layout: wp[g8][k4][c][j], k = k4*4+j, c = cell_loc*4+gate;
// source gate-row = gate*H + g8*2 + cell_loc; k concatenates [x-part | h-part].
__global__ __launch_bounds__(256) void pack_w_kernel(
    const float* __restrict__ wx0, const float* __restrict__ wh0,
    const float* __restrict__ wx1, const float* __restrict__ wh1,
    float* __restrict__ wp0, float* __restrict__ wp1) {
  const int idx = blockIdx.x * 256 + threadIdx.x;
  if (idx < WP0_FLOATS) {
    const int j = idx & 3;
    const int c = (idx >> 2) & 7;
    const int k4 = (idx >> 5) % 192;
    const int g8 = (idx >> 5) / 192;
    const int k = k4 * 4 + j;
    const int row = (c & 3) * HH + g8 * 2 + (c >> 2);
    wp0[idx] = (k < DD) ? wx0[(size_t)row * DD + k] : wh0[(size_t)row * HH + (k - DD)];
  }
  if (idx < WP1_FLOATS) {
    const int j = idx & 3;
    const int c = (idx >> 2) & 7;
    const int k4 = (idx >> 5) & 255;
    const int g8 = (idx >> 5) >> 8;
    const int k = k4 * 4 + j;
    const int row = (c & 3) * HH + g8 * 2 + (c >> 2);
    wp1[idx] = (k < HH) ? wx1[(size_t)row * HH + k] : wh1[(size_t)row * HH + (k - HH)];
  }
}

// ================= PRIMARY: 512 blocks x 256 thr, split-K =================
// 2 blocks/CU (launch_bounds(256,2), LDS 24576 B). Block: rowhalf x 16 gate-
// cols; 4 waves = 2 g8 x 2 K-halves; lane <-> row. W: wave-uniform broadcast
// float4 loads, ping-pong one-k8 lookahead (two named buffers, no copies).
// A (x||h) staged in 32-k tiles per half in LDS.

#define AP2 36  // 32 k + 4 pad
#define RP2 12  // reduction pitch

// dot with pack layout [k4][c][j]: WB[c] = col c, k 0..3; WB[8+c] = col c, k 4..7
#define K8C(K8L, WB)                                                 \
  do {                                                               \
    const float4 a0 = *(const float4*)&At[atbase + (K8L) * 8];       \
    const float4 a1 = *(const float4*)&At[atbase + (K8L) * 8 + 4];   \
    _Pragma("unroll") for (int c_ = 0; c_ < 8; ++c_) {               \
      const float4 wA = WB[c_];                                      \
      const float4 wB_ = WB[8 + c_];                                 \
      acc[c_] = fmaf(a0.x, wA.x, acc[c_]);                           \
      acc[c_] = fmaf(a0.y, wA.y, acc[c_]);                           \
      acc[c_] = fmaf(a0.z, wA.z, acc[c_]);                           \
      acc[c_] = fmaf(a0.w, wA.w, acc[c_]);                           \
      acc[c_] = fmaf(a1.x, wB_.x, acc[c_]);                          \
      acc[c_] = fmaf(a1.y, wB_.y, acc[c_]);                          \
      acc[c_] = fmaf(a1.z, wB_.z, acc[c_]);                          \
      acc[c_] = fmaf(a1.w, wB_.w, acc[c_]);                          \
    }                                                                \
  } while (0)

#define WLOAD(DST, QQ)                                                   \
  do {                                                                   \
    const int q_ = (QQ) < nk8h ? (QQ) : (nk8h - 1);                      \
    const float4* s_ = wbase + (size_t)q_ * 16;                          \
    _Pragma("unroll") for (int i_ = 0; i_ < 16; ++i_) DST[i_] = s_[i_];  \
  } while (0)

__global__ __launch_bounds__(256, 2) void lstm512_kernel(
    const float* __restrict__ xp,
    const float* __restrict__ wp0, const float* __restrict__ wp1,
    const float* __restrict__ bx0, const float* __restrict__ bh0,
    const float* __restrict__ bx1, const float* __restrict__ bh1,
    float* __restrict__ h0buf, float* __restrict__ h1buf) {
  cg::grid_group grid = cg::this_grid();
  __shared__ float At[2 * 64 * AP2];   // [half][row][k-local 32]
  __shared__ float red[2 * 64 * RP2];  // [g8i][lane][8 partials]

  const int bidx = blockIdx.x;
  const int role = bidx >> 8;
  const int lid = bidx & 255;
  const int m0 = (lid >> 7) * 64;
  const int gcblk = lid & 127;
  const int tid = threadIdx.x;
  const int w = tid >> 6;
  const int g8i = w >> 1;
  const int kh = w & 1;
  const int lane = tid & 63;
  const int g8 = gcblk * 2 + g8i;
  const int atbase = (kh * 64 + lane) * AP2;
  // staging: half sh, row sr, 16-float chunk sq
  const int sh = tid >> 7;
  const int sr = (tid & 127) >> 1;
  const int sq = tid & 1;

  {  // zero initial h (512*256 covers 2*BB*HH exactly)
    const int i = bidx * 256 + tid;
    h0buf[i] = 0.0f;
    h1buf[i] = 0.0f;
  }
  __threadfence();
  grid.sync();

  const float* wp = role ? wp1 : wp0;
  const float* bx = role ? bx1 : bx0;
  const float* bh = role ? bh1 : bh0;
  const int KX = role ? HH : DD;
  const int K = KX + HH;
  const int Khalf = K >> 1;        // 384 / 512
  const int nth = Khalf >> 5;      // 12 / 16 tiles (32-k) per half
  const int nk8h = Khalf >> 3;     // 48 / 64
  const float4* wbase =
      (const float4*)(wp + (size_t)g8 * K * 8 + (size_t)kh * Khalf * 8);

  float bg[8];
#pragma unroll
  for (int c = 0; c < 8; ++c) {
    const int gate = c & 3, cl = c >> 2;
    const int cg = g8 * 2 + cl;
    bg[c] = bx[gate * HH + cg] + bh[gate * HH + cg];
  }
  float cst[2] = {0.f, 0.f};

  for (int p = 0; p <= TT; ++p) {
    const bool active = role ? (p >= 1) : (p < TT);
    if (active) {
      const int t = role ? (p - 1) : p;
      const int rdbuf = (p + 1) & 1;
      const int wrbuf = p & 1;
      const float* hprev = (role ? h1buf : h0buf) + (size_t)rdbuf * BB * HH;
      const float* xsrc;
      size_t xpitch;
      if (role) { xsrc = h0buf + (size_t)rdbuf * BB * HH; xpitch = HH; }
      else      { xsrc = xp + (size_t)t * DD;             xpitch = (size_t)TT * DD; }

      float acc[8] = {0.f, 0.f, 0.f, 0.f, 0.f, 0.f, 0.f, 0.f};

      // prefetch A tile 0 (16 floats per thread)
      float4 st[4];
      {
        const int kg = sh * Khalf + sq * 16;
        const float* s = (kg < KX) ? xsrc + (size_t)(m0 + sr) * xpitch + kg
                                   : hprev + (size_t)(m0 + sr) * HH + (kg - KX);
#pragma unroll
        for (int i = 0; i < 4; ++i) st[i] = ((const float4*)s)[i];
      }
      float4 w0[16], w1[16];
      WLOAD(w0, 0);

      for (int t32 = 0; t32 < nth; ++t32) {
        __syncthreads();  // previous tile consumed
        {
          float* d = &At[(sh * 64 + sr) * AP2 + sq * 16];
#pragma unroll
          for (int i = 0; i < 4; ++i) ((float4*)d)[i] = st[i];
        }
        __syncthreads();
        if (t32 + 1 < nth) {  // prefetch next tile (overlaps compute)
          const int kg = sh * Khalf + (t32 + 1) * 32 + sq * 16;
          const float* s = (kg < KX) ? xsrc + (size_t)(m0 + sr) * xpitch + kg
                                     : hprev + (size_t)(m0 + sr) * HH + (kg - KX);
#pragma unroll
          for (int i = 0; i < 4; ++i) st[i] = ((const float4*)s)[i];
        }
        const int qq0 = t32 * 4;
        WLOAD(w1, qq0 + 1);
        K8C(0, w0);
        WLOAD(w0, qq0 + 2);
        K8C(1, w1);
        WLOAD(w1, qq0 + 3);
        K8C(2, w0);
        WLOAD(w0, qq0 + 4);
        K8C(3, w1);
      }

      // split-K reduction: kh=1 -> LDS -> kh=0
      if (kh == 1) {
        float* r = &red[(g8i * 64 + lane) * RP2];
        *(float4*)r = make_float4(acc[0], acc[1], acc[2], acc[3]);
        *(float4*)(r + 4) = make_float4(acc[4], acc[5], acc[6], acc[7]);
      }
      __syncthreads();
      if (kh == 0) {
        const float* r = &red[(g8i * 64 + lane) * RP2];
        const float4 r0 = *(const float4*)r;
        const float4 r1 = *(const float4*)(r + 4);
        acc[0] += r0.x; acc[1] += r0.y; acc[2] += r0.z; acc[3] += r0.w;
        acc[4] += r1.x; acc[5] += r1.y; acc[6] += r1.z; acc[7] += r1.w;
        float* hout = (role ? h1buf : h0buf) + (size_t)wrbuf * BB * HH;
        float2 hv;
#pragma unroll
        for (int cl = 0; cl < 2; ++cl) {
          const float iv = acc[cl * 4 + 0] + bg[cl * 4 + 0];
          const float fv = acc[cl * 4 + 1] + bg[cl * 4 + 1];
          const float gv = acc[cl * 4 + 2] + bg[cl * 4 + 2];
          const float ov = acc[cl * 4 + 3] + bg[cl * 4 + 3];
          const float cn = sig_(fv) * cst[cl] + sig_(iv) * tanhf(gv);
          cst[cl] = cn;
          const float hnv = sig_(ov) * tanhf(cn);
          if (cl == 0) hv.x = hnv; else hv.y = hnv;
        }
        *(float2*)&hout[(size_t)(m0 + lane) * HH + g8 * 2] = hv;
      }
    }
    __threadfence();
    grid.sync();
  }
}

// ============ FALLBACK: round-2 proven kernel (256 blocks x 256 thr) ============
#define APF 68

__global__ __launch_bounds__(256, 1) void lstm_fb_kernel(
    const float* __restrict__ xp,
    const float* __restrict__ wp0, const float* __restrict__ wp1,
    const float* __restrict__ bx0, const float* __restrict__ bh0,
    const float* __restrict__ bx1, const float* __restrict__ bh1,
    float* __restrict__ h0buf, float* __restrict__ h1buf) {
  cg::grid_group grid = cg::this_grid();
  __shared__ float At[64 * APF];
  const int bidx = blockIdx.x;
  const int role = bidx >> 7;
  const int lid = bidx & 127;
  const int m0 = (lid >> 6) * 64;
  const int gcblk = lid & 63;
  const int tid = threadIdx.x;
  const int w = tid >> 6;
  const int lane = tid & 63;
  const int g8 = gcblk * 4 + w;

  for (int i = bidx * 256 + tid; i < 2 * BB * HH; i += 256 * 256) {
    h0buf[i] = 0.0f;
    h1buf[i] = 0.0f;
  }
  __threadfence();
  grid.sync();

  const float* wp = role ? wp1 : wp0;
  const float* bx = role ? bx1 : bx0;
  const float* bh = role ? bh1 : bh0;
  const int KX = role ? HH : DD;
  const int K = KX + HH;
  const int ntiles = K >> 6;
  const int nk8 = K >> 3;
  const float* wpg = wp + (size_t)g8 * K * 8;

  float bg[8];
#pragma unroll
  for (int c = 0; c < 8; ++c) {
    const int gate = c & 3, cl = c >> 2;
    const int cg = g8 * 2 + cl;
    bg[c] = bx[gate * HH + cg] + bh[gate * HH + cg];
  }
  float cst[2] = {0.f, 0.f};

  const int srow = tid >> 2;
  const int sq = tid & 3;

  for (int p = 0; p <= TT; ++p) {
    const bool active = role ? (p >= 1) : (p < TT);
    if (active) {
      const int t = role ? (p - 1) : p;
      const int rdbuf = (p + 1) & 1;
      const int wrbuf = p & 1;
      const float* hprev = (role ? h1buf : h0buf) + (size_t)rdbuf * BB * HH;
      const float* xsrc;
      size_t xpitch;
      if (role) { xsrc = h0buf + (size_t)rdbuf * BB * HH; xpitch = HH; }
      else      { xsrc = xp + (size_t)t * DD;             xpitch = (size_t)TT * DD; }

      float acc[8] = {0.f, 0.f, 0.f, 0.f, 0.f, 0.f, 0.f, 0.f};
      float4 st[4];
      {
        const int ks = sq * 16;
        const float* s = (ks < KX) ? xsrc + (size_t)(m0 + srow) * xpitch + ks
                                   : hprev + (size_t)(m0 + srow) * HH + (ks - KX);
#pragma unroll
        for (int i = 0; i < 4; ++i) st[i] = ((const float4*)s)[i];
      }
      float4 wcur[16], wnxt[16];
#pragma unroll
      for (int i = 0; i < 16; ++i) wcur[i] = ((const float4*)wpg)[i];
      int k8g = 0;

      for (int kt = 0; kt < ntiles; ++kt) {
        __syncthreads();
        {
          float* d = &At[srow * APF + sq * 16];
#pragma unroll
          for (int i = 0; i < 4; ++i) ((float4*)d)[i] = st[i];
        }
        __syncthreads();
        if (kt + 1 < ntiles) {
          const int ks = ((kt + 1) << 6) + sq * 16;
          const float* s = (ks < KX) ? xsrc + (size_t)(m0 + srow) * xpitch + ks
                                     : hprev + (size_t)(m0 + srow) * HH + (ks - KX);
#pragma unroll
          for (int i = 0; i < 4; ++i) st[i] = ((const float4*)s)[i];
        }
#pragma unroll
        for (int k8 = 0; k8 < 8; ++k8) {
          const int nk = (k8g + 1 < nk8) ? (k8g + 1) : (nk8 - 1);
          const float4* s = (const float4*)(wpg + (size_t)nk * 64);
#pragma unroll
          for (int i = 0; i < 16; ++i) wnxt[i] = s[i];
          const float4 a0 = *(const float4*)&At[lane * APF + k8 * 8];
          const float4 a1 = *(const float4*)&At[lane * APF + k8 * 8 + 4];
#pragma unroll
          for (int c = 0; c < 8; ++c) {
            const float4 wA = wcur[c];
            const float4 wB = wcur[8 + c];
            acc[c] = fmaf(a0.x, wA.x, acc[c]);
            acc[c] = fmaf(a0.y, wA.y, acc[c]);
            acc[c] = fmaf(a0.z, wA.z, acc[c]);
            acc[c] = fmaf(a0.w, wA.w, acc[c]);
            acc[c] = fmaf(a1.x, wB.x, acc[c]);
            acc[c] = fmaf(a1.y, wB.y, acc[c]);
            acc[c] = fmaf(a1.z, wB.z, acc[c]);
            acc[c] = fmaf(a1.w, wB.w, acc[c]);
          }
#pragma unroll
          for (int i = 0; i < 16; ++i) wcur[i] = wnxt[i];
          ++k8g;
        }
      }
      float* hout = (role ? h1buf : h0buf) + (size_t)wrbuf * BB * HH;
      float2 hv;
#pragma unroll
      for (int cl = 0; cl < 2; ++cl) {
        const float iv = acc[cl * 4 + 0] + bg[cl * 4 + 0];
        const float fv = acc[cl * 4 + 1] + bg[cl * 4 + 1];
        const float gv = acc[cl * 4 + 2] + bg[cl * 4 + 2];
        const float ov = acc[cl * 4 + 3] + bg[cl * 4 + 3];
        const float cn = sig_(fv) * cst[cl] + sig_(iv) * tanhf(gv);
        cst[cl] = cn;
        const float hnv = sig_(ov) * tanhf(cn);
        if (cl == 0) hv.x = hnv; else hv.y = hnv;
      }
      *(float2*)&hout[(size_t)(m0 + lane) * HH + g8 * 2] = hv;
    }
    __threadfence();
    grid.sync();
  }
}

// ---------------- head ----------------
__global__ __launch_bounds__(256) void head_kernel(const float* __restrict__ h1,
                                                   const float* __restrict__ fc1w,
                                                   const float* __restrict__ fc1b,
                                                   const float* __restrict__ fc2w,
                                                   const float* __restrict__ fc2b,
                                                   float* __restrict__ out) {
  __shared__ float part[256];
  __shared__ float hid[32];
  const int r = blockIdx.x;
  const int tid = threadIdx.x;
  const int c = tid & 31, pt = tid >> 5;
  const float4* ha = (const float4*)(h1 + (size_t)r * HH + pt * 64);
  const float4* wa = (const float4*)(fc1w + (size_t)c * HH + pt * 64);
  float s = 0.f;
#pragma unroll
  for (int j = 0; j < 16; ++j) {
    float4 av = ha[j], wv = wa[j];
    s = fmaf(av.x, wv.x, s);
    s = fmaf(av.y, wv.y, s);
    s = fmaf(av.z, wv.z, s);
    s = fmaf(av.w, wv.w, s);
  }
  part[tid] = s;
  __syncthreads();
  if (tid < 32) {
    float v = fc1b[tid];
#pragma unroll
    for (int q = 0; q < 8; ++q) v += part[q * 32 + tid];
    hid[tid] = fmaxf(v, 0.f);
  }
  __syncthreads();
  if (tid == 0) {
    float v = fc2b[0];
    for (int cc = 0; cc < 32; ++cc) v = fmaf(hid[cc], fc2w[cc], v);
    out[r] = v;
  }
}

extern "C" void kernel_launch(void* const* d_in, const int* in_sizes, int n_in,
                              void* d_out, int out_size, void* d_ws, size_t ws_size,
                              hipStream_t stream) {
  const float* x    = (const float*)d_in[0];
  const float* pw   = (const float*)d_in[1];
  const float* pb   = (const float*)d_in[2];
  const float* wx0  = (const float*)d_in[3];
  const float* bx0  = (const float*)d_in[4];
  const float* wh0  = (const float*)d_in[5];
  const float* bh0  = (const float*)d_in[6];
  const float* wx1  = (const float*)d_in[7];
  const float* bx1  = (const float*)d_in[8];
  const float* wh1  = (const float*)d_in[9];
  const float* bh1  = (const float*)d_in[10];
  const float* fc1w = (const float*)d_in[11];
  const float* fc1b = (const float*)d_in[12];
  const float* fc2w = (const float*)d_in[13];
  const float* fc2b = (const float*)d_in[14];
  float* out = (float*)d_out;

  float* xp = (float*)d_ws;
  float* h0buf = xp + (size_t)BB * TT * DD;
  float* h1buf = h0buf + 2 * BB * HH;
  float* wp0 = h1buf + 2 * BB * HH;
  float* wp1 = wp0 + WP0_FLOATS;

  proj_kernel<<<dim3(4096), dim3(256), 0, stream>>>(x, pw, pb, xp);
  pack_w_kernel<<<dim3((WP1_FLOATS + 255) / 256), dim3(256), 0, stream>>>(
      wx0, wh0, wx1, wh1, wp0, wp1);

  void* kargs[] = {(void*)&xp,  (void*)&wp0, (void*)&wp1, (void*)&bx0,
                   (void*)&bh0, (void*)&bx1, (void*)&bh1, (void*)&h0buf,
                   (void*)&h1buf};
  hipError_t err = hipLaunchCooperativeKernel((void*)lstm512_kernel, dim3(512),
                                              dim3(256), kargs, 0, stream);
  if (err != hipSuccess) {
    (void)hipGetLastError();  // clear sticky error; use proven 256-block kernel
    hipLaunchCooperativeKernel((void*)lstm_fb_kernel, dim3(256), dim3(256),
                               kargs, 0, stream);
  }

  head_kernel<<<dim3(BB), dim3(256), 0, stream>>>(h1buf, fc1w, fc1b, fc2w, fc2b, out);
}

// Round 6
// 89265.173 us; speedup vs baseline: 1.1772x; 1.1772x over previous
//
#include <hip/hip_runtime.h>
#include <hip/hip_cooperative_groups.h>

namespace cg = cooperative_groups;

#define BB 128
#define TT 512
#define DD 256
#define HH 512

#define WP0_FLOATS (2048 * 768)   // L0 packed weights
#define WP1_FLOATS (2048 * 1024)  // L1 packed weights

__device__ __forceinline__ float sig_(float x) { return 1.0f / (1.0f + __expf(-x)); }

// ---------------- projection GEMM: xp = x @ proj_w.T + proj_b ----------------
__global__ __launch_bounds__(256) void proj_kernel(const float* __restrict__ x,
                                                   const float* __restrict__ pw,
                                                   const float* __restrict__ pb,
                                                   float* __restrict__ xp) {
  __shared__ float At[64 * 68];
  __shared__ float Bt[64 * 68];
  const int bm = blockIdx.x >> 2;
  const int bn = blockIdx.x & 3;
  const int tid = threadIdx.x;
  const int rg = tid >> 4;
  const int cgi = tid & 15;
  const int m0 = bm * 64, n0 = bn * 64;
  float acc[4][4] = {};
  for (int kt = 0; kt < 4; ++kt) {
    const int k0 = kt * 64;
    {
      const int r = tid >> 2, q = tid & 3;
      const float4* src = (const float4*)(x + (size_t)(m0 + r) * DD + k0 + q * 16);
      float4* dst = (float4*)&At[r * 68 + q * 16];
#pragma unroll
      for (int j = 0; j < 4; ++j) dst[j] = src[j];
    }
    {
      const int n = tid & 63, kg = tid >> 6;
      const float4* src = (const float4*)(pw + (size_t)(n0 + n) * DD + k0 + kg * 16);
#pragma unroll
      for (int j = 0; j < 4; ++j) {
        float4 v = src[j];
        const int kk = kg * 16 + j * 4;
        Bt[(kk + 0) * 68 + n] = v.x;
        Bt[(kk + 1) * 68 + n] = v.y;
        Bt[(kk + 2) * 68 + n] = v.z;
        Bt[(kk + 3) * 68 + n] = v.w;
      }
    }
    __syncthreads();
#pragma unroll
    for (int k4 = 0; k4 < 64; k4 += 4) {
      float4 a[4], b[4];
#pragma unroll
      for (int j = 0; j < 4; ++j) a[j] = *(const float4*)&At[(rg * 4 + j) * 68 + k4];
#pragma unroll
      for (int j = 0; j < 4; ++j) b[j] = *(const float4*)&Bt[(k4 + j) * 68 + cgi * 4];
#pragma unroll
      for (int jr = 0; jr < 4; ++jr) {
#pragma unroll
        for (int q = 0; q < 4; ++q) {
          const float av = q == 0 ? a[jr].x : q == 1 ? a[jr].y : q == 2 ? a[jr].z : a[jr].w;
          acc[jr][0] = fmaf(av, b[q].x, acc[jr][0]);
          acc[jr][1] = fmaf(av, b[q].y, acc[jr][1]);
          acc[jr][2] = fmaf(av, b[q].z, acc[jr][2]);
          acc[jr][3] = fmaf(av, b[q].w, acc[jr][3]);
        }
      }
    }
    __syncthreads();
  }
  const float4 bias = *(const float4*)&pb[n0 + cgi * 4];
#pragma unroll
  for (int jr = 0; jr < 4; ++jr) {
    float4 o;
    o.x = acc[jr][0] + bias.x;
    o.y = acc[jr][1] + bias.y;
    o.z = acc[jr][2] + bias.z;
    o.w = acc[jr][3] + bias.w;
    *(float4*)&xp[(size_t)(m0 + rg * 4 + jr) * DD + n0 + cgi * 4] = o;
  }
}

// ---------------- weight pack (layout validated rounds 2 & 4) ----------------
// wp[g8][k4][c][j], k = k4*4+j, c = cell_loc*4+gate;
// source gate-row = gate*H + g8*2 + cell_loc; k concatenates [x-part | h-part].
__global__ __launch_bounds__(256) void pack_w_kernel(
    const float* __restrict__ wx0, const float* __restrict__ wh0,
    const float* __restrict__ wx1, const float* __restrict__ wh1,
    float* __restrict__ wp0, float* __restrict__ wp1) {
  const int idx = blockIdx.x * 256 + threadIdx.x;
  if (idx < WP0_FLOATS) {
    const int j = idx & 3;
    const int c = (idx >> 2) & 7;
    const int k4 = (idx >> 5) % 192;
    const int g8 = (idx >> 5) / 192;
    const int k = k4 * 4 + j;
    const int row = (c & 3) * HH + g8 * 2 + (c >> 2);
    wp0[idx] = (k < DD) ? wx0[(size_t)row * DD + k] : wh0[(size_t)row * HH + (k - DD)];
  }
  if (idx < WP1_FLOATS) {
    const int j = idx & 3;
    const int c = (idx >> 2) & 7;
    const int k4 = (idx >> 5) & 255;
    const int g8 = (idx >> 5) >> 8;
    const int k = k4 * 4 + j;
    const int row = (c & 3) * HH + g8 * 2 + (c >> 2);
    wp1[idx] = (k < HH) ? wx1[(size_t)row * HH + k] : wh1[(size_t)row * HH + (k - HH)];
  }
}

// ================= PRIMARY: 512 blocks x 256 thr, split-K =================
// Round-4 structure (passed) with ALL per-thread hot arrays replaced by NAMED
// registers (rounds 2/4: compiler left float4 arrays in scratch -> ~10 GB
// WRITE_SIZE). W ping-pong = 2 banks x 8 named float4. Variadic two-level
// macros so WA/WB expand during prescan (round-5 compile fix).

#define AP2 36  // 32 k + 4 pad  (SQ_LDS_BANK_CONFLICT == 0 measured)
#define RP2 12

#define WLD_I(QQ, D0, D1, D2, D3, D4, D5, D6, D7)          \
  do {                                                     \
    const int q_ = (QQ) < nk4h ? (QQ) : (nk4h - 1);        \
    const float4* s_ = wbase4 + (size_t)q_ * 8;            \
    D0 = s_[0]; D1 = s_[1]; D2 = s_[2]; D3 = s_[3];        \
    D4 = s_[4]; D5 = s_[5]; D6 = s_[6]; D7 = s_[7];        \
  } while (0)
#define WLD(QQ, ...) WLD_I(QQ, __VA_ARGS__)

#define WFMA_I(SS, W0, W1, W2, W3, W4, W5, W6, W7)                     \
  do {                                                                 \
    const float4 af_ = *(const float4*)&At[atbase + (SS) * 4];         \
    acc0 = fmaf(af_.x, (W0).x, acc0); acc0 = fmaf(af_.y, (W0).y, acc0);\
    acc0 = fmaf(af_.z, (W0).z, acc0); acc0 = fmaf(af_.w, (W0).w, acc0);\
    acc1 = fmaf(af_.x, (W1).x, acc1); acc1 = fmaf(af_.y, (W1).y, acc1);\
    acc1 = fmaf(af_.z, (W1).z, acc1); acc1 = fmaf(af_.w, (W1).w, acc1);\
    acc2 = fmaf(af_.x, (W2).x, acc2); acc2 = fmaf(af_.y, (W2).y, acc2);\
    acc2 = fmaf(af_.z, (W2).z, acc2); acc2 = fmaf(af_.w, (W2).w, acc2);\
    acc3 = fmaf(af_.x, (W3).x, acc3); acc3 = fmaf(af_.y, (W3).y, acc3);\
    acc3 = fmaf(af_.z, (W3).z, acc3); acc3 = fmaf(af_.w, (W3).w, acc3);\
    acc4 = fmaf(af_.x, (W4).x, acc4); acc4 = fmaf(af_.y, (W4).y, acc4);\
    acc4 = fmaf(af_.z, (W4).z, acc4); acc4 = fmaf(af_.w, (W4).w, acc4);\
    acc5 = fmaf(af_.x, (W5).x, acc5); acc5 = fmaf(af_.y, (W5).y, acc5);\
    acc5 = fmaf(af_.z, (W5).z, acc5); acc5 = fmaf(af_.w, (W5).w, acc5);\
    acc6 = fmaf(af_.x, (W6).x, acc6); acc6 = fmaf(af_.y, (W6).y, acc6);\
    acc6 = fmaf(af_.z, (W6).z, acc6); acc6 = fmaf(af_.w, (W6).w, acc6);\
    acc7 = fmaf(af_.x, (W7).x, acc7); acc7 = fmaf(af_.y, (W7).y, acc7);\
    acc7 = fmaf(af_.z, (W7).z, acc7); acc7 = fmaf(af_.w, (W7).w, acc7);\
  } while (0)
#define WFMA(SS, ...) WFMA_I(SS, __VA_ARGS__)

#define WA wa0, wa1, wa2, wa3, wa4, wa5, wa6, wa7
#define WB wb0, wb1, wb2, wb3, wb4, wb5, wb6, wb7

__global__ __launch_bounds__(256, 3) void lstm512_kernel(
    const float* __restrict__ xp,
    const float* __restrict__ wp0, const float* __restrict__ wp1,
    const float* __restrict__ bx0, const float* __restrict__ bh0,
    const float* __restrict__ bx1, const float* __restrict__ bh1,
    float* __restrict__ h0buf, float* __restrict__ h1buf) {
  cg::grid_group grid = cg::this_grid();
  __shared__ float At[2 * 64 * AP2];
  __shared__ float red[2 * 64 * RP2];

  const int bidx = blockIdx.x;
  const int role = bidx >> 8;
  const int lid = bidx & 255;
  const int m0 = (lid >> 7) * 64;
  const int gcblk = lid & 127;
  const int tid = threadIdx.x;
  const int w = tid >> 6;
  const int g8i = w >> 1;
  const int kh = w & 1;
  const int lane = tid & 63;
  const int g8 = gcblk * 2 + g8i;
  const int atbase = (kh * 64 + lane) * AP2;
  const int sh = tid >> 7;
  const int sr = (tid & 127) >> 1;
  const int sq = tid & 1;

  {  // zero initial h (512*256 == 2*BB*HH exactly)
    const int i = bidx * 256 + tid;
    h0buf[i] = 0.0f;
    h1buf[i] = 0.0f;
  }
  __threadfence();
  grid.sync();

  const float* wp = role ? wp1 : wp0;
  const float* bx = role ? bx1 : bx0;
  const float* bh = role ? bh1 : bh0;
  const int KX = role ? HH : DD;
  const int K = KX + HH;
  const int Khalf = K >> 1;       // 384 / 512
  const int nth = Khalf >> 5;     // 12 / 16
  const int nk4h = Khalf >> 2;    // 96 / 128
  const float4* wbase4 =
      (const float4*)(wp + (size_t)g8 * K * 8 + (size_t)kh * Khalf * 8);

  float bg0, bg1, bg2, bg3, bg4, bg5, bg6, bg7;
  {
    const int cg0 = g8 * 2, cg1 = g8 * 2 + 1;
    bg0 = bx[0 * HH + cg0] + bh[0 * HH + cg0];
    bg1 = bx[1 * HH + cg0] + bh[1 * HH + cg0];
    bg2 = bx[2 * HH + cg0] + bh[2 * HH + cg0];
    bg3 = bx[3 * HH + cg0] + bh[3 * HH + cg0];
    bg4 = bx[0 * HH + cg1] + bh[0 * HH + cg1];
    bg5 = bx[1 * HH + cg1] + bh[1 * HH + cg1];
    bg6 = bx[2 * HH + cg1] + bh[2 * HH + cg1];
    bg7 = bx[3 * HH + cg1] + bh[3 * HH + cg1];
  }
  float cst0 = 0.f, cst1 = 0.f;

  for (int p = 0; p <= TT; ++p) {
    const bool active = role ? (p >= 1) : (p < TT);
    if (active) {
      const int t = role ? (p - 1) : p;
      const int rdbuf = (p + 1) & 1;
      const int wrbuf = p & 1;
      const float* hprev = (role ? h1buf : h0buf) + (size_t)rdbuf * BB * HH;
      const float* xsrc;
      size_t xpitch;
      if (role) { xsrc = h0buf + (size_t)rdbuf * BB * HH; xpitch = HH; }
      else      { xsrc = xp + (size_t)t * DD;             xpitch = (size_t)TT * DD; }

      float acc0 = 0.f, acc1 = 0.f, acc2 = 0.f, acc3 = 0.f;
      float acc4 = 0.f, acc5 = 0.f, acc6 = 0.f, acc7 = 0.f;

      // prefetch A tile 0 (named regs)
      float4 st0, st1, st2, st3;
      {
        const int kg = sh * Khalf + sq * 16;
        const float* s = (kg < KX) ? xsrc + (size_t)(m0 + sr) * xpitch + kg
                                   : hprev + (size_t)(m0 + sr) * HH + (kg - KX);
        const float4* s4 = (const float4*)s;
        st0 = s4[0]; st1 = s4[1]; st2 = s4[2]; st3 = s4[3];
      }
      float4 wa0, wa1, wa2, wa3, wa4, wa5, wa6, wa7;
      float4 wb0, wb1, wb2, wb3, wb4, wb5, wb6, wb7;
      WLD(0, WA);

      for (int t32 = 0; t32 < nth; ++t32) {
        __syncthreads();
        {
          float4* d = (float4*)&At[(sh * 64 + sr) * AP2 + sq * 16];
          d[0] = st0; d[1] = st1; d[2] = st2; d[3] = st3;
        }
        __syncthreads();
        if (t32 + 1 < nth) {
          const int kg = sh * Khalf + (t32 + 1) * 32 + sq * 16;
          const float* s = (kg < KX) ? xsrc + (size_t)(m0 + sr) * xpitch + kg
                                     : hprev + (size_t)(m0 + sr) * HH + (kg - KX);
          const float4* s4 = (const float4*)s;
          st0 = s4[0]; st1 = s4[1]; st2 = s4[2]; st3 = s4[3];
        }
        const int q0 = t32 * 8;
        WLD(q0 + 1, WB);
        WFMA(0, WA);
        WLD(q0 + 2, WA);
        WFMA(1, WB);
        WLD(q0 + 3, WB);
        WFMA(2, WA);
        WLD(q0 + 4, WA);
        WFMA(3, WB);
        WLD(q0 + 5, WB);
        WFMA(4, WA);
        WLD(q0 + 6, WA);
        WFMA(5, WB);
        WLD(q0 + 7, WB);
        WFMA(6, WA);
        WLD(q0 + 8, WA);
        WFMA(7, WB);
      }

      // split-K reduction: kh=1 -> LDS -> kh=0
      if (kh == 1) {
        float* r = &red[(g8i * 64 + lane) * RP2];
        *(float4*)r = make_float4(acc0, acc1, acc2, acc3);
        *(float4*)(r + 4) = make_float4(acc4, acc5, acc6, acc7);
      }
      __syncthreads();
      if (kh == 0) {
        const float* r = &red[(g8i * 64 + lane) * RP2];
        const float4 r0 = *(const float4*)r;
        const float4 r1 = *(const float4*)(r + 4);
        acc0 += r0.x; acc1 += r0.y; acc2 += r0.z; acc3 += r0.w;
        acc4 += r1.x; acc5 += r1.y; acc6 += r1.z; acc7 += r1.w;
        float* hout = (role ? h1buf : h0buf) + (size_t)wrbuf * BB * HH;
        float2 hv;
        {
          const float cn = sig_(acc1 + bg1) * cst0 +
                           sig_(acc0 + bg0) * tanhf(acc2 + bg2);
          cst0 = cn;
          hv.x = sig_(acc3 + bg3) * tanhf(cn);
        }
        {
          const float cn = sig_(acc5 + bg5) * cst1 +
                           sig_(acc4 + bg4) * tanhf(acc6 + bg6);
          cst1 = cn;
          hv.y = sig_(acc7 + bg7) * tanhf(cn);
        }
        *(float2*)&hout[(size_t)(m0 + lane) * HH + g8 * 2] = hv;
      }
    }
    __threadfence();
    grid.sync();
  }
}

// ============ FALLBACK: round-2 proven kernel (256 blocks x 256 thr) ============
#define APF 68

__global__ __launch_bounds__(256, 1) void lstm_fb_kernel(
    const float* __restrict__ xp,
    const float* __restrict__ wp0, const float* __restrict__ wp1,
    const float* __restrict__ bx0, const float* __restrict__ bh0,
    const float* __restrict__ bx1, const float* __restrict__ bh1,
    float* __restrict__ h0buf, float* __restrict__ h1buf) {
  cg::grid_group grid = cg::this_grid();
  __shared__ float At[64 * APF];
  const int bidx = blockIdx.x;
  const int role = bidx >> 7;
  const int lid = bidx & 127;
  const int m0 = (lid >> 6) * 64;
  const int gcblk = lid & 63;
  const int tid = threadIdx.x;
  const int w = tid >> 6;
  const int lane = tid & 63;
  const int g8 = gcblk * 4 + w;

  for (int i = bidx * 256 + tid; i < 2 * BB * HH; i += 256 * 256) {
    h0buf[i] = 0.0f;
    h1buf[i] = 0.0f;
  }
  __threadfence();
  grid.sync();

  const float* wp = role ? wp1 : wp0;
  const float* bx = role ? bx1 : bx0;
  const float* bh = role ? bh1 : bh0;
  const int KX = role ? HH : DD;
  const int K = KX + HH;
  const int ntiles = K >> 6;
  const int nk8 = K >> 3;
  const float* wpg = wp + (size_t)g8 * K * 8;

  float bg[8];
#pragma unroll
  for (int c = 0; c < 8; ++c) {
    const int gate = c & 3, cl = c >> 2;
    const int cg = g8 * 2 + cl;
    bg[c] = bx[gate * HH + cg] + bh[gate * HH + cg];
  }
  float cst[2] = {0.f, 0.f};

  const int srow = tid >> 2;
  const int sq = tid & 3;

  for (int p = 0; p <= TT; ++p) {
    const bool active = role ? (p >= 1) : (p < TT);
    if (active) {
      const int t = role ? (p - 1) : p;
      const int rdbuf = (p + 1) & 1;
      const int wrbuf = p & 1;
      const float* hprev = (role ? h1buf : h0buf) + (size_t)rdbuf * BB * HH;
      const float* xsrc;
      size_t xpitch;
      if (role) { xsrc = h0buf + (size_t)rdbuf * BB * HH; xpitch = HH; }
      else      { xsrc = xp + (size_t)t * DD;             xpitch = (size_t)TT * DD; }

      float acc[8] = {0.f, 0.f, 0.f, 0.f, 0.f, 0.f, 0.f, 0.f};
      float4 st[4];
      {
        const int ks = sq * 16;
        const float* s = (ks < KX) ? xsrc + (size_t)(m0 + srow) * xpitch + ks
                                   : hprev + (size_t)(m0 + srow) * HH + (ks - KX);
#pragma unroll
        for (int i = 0; i < 4; ++i) st[i] = ((const float4*)s)[i];
      }
      float4 wcur[16], wnxt[16];
#pragma unroll
      for (int i = 0; i < 16; ++i) wcur[i] = ((const float4*)wpg)[i];
      int k8g = 0;

      for (int kt = 0; kt < ntiles; ++kt) {
        __syncthreads();
        {
          float* d = &At[srow * APF + sq * 16];
#pragma unroll
          for (int i = 0; i < 4; ++i) ((float4*)d)[i] = st[i];
        }
        __syncthreads();
        if (kt + 1 < ntiles) {
          const int ks = ((kt + 1) << 6) + sq * 16;
          const float* s = (ks < KX) ? xsrc + (size_t)(m0 + srow) * xpitch + ks
                                     : hprev + (size_t)(m0 + srow) * HH + (ks - KX);
#pragma unroll
          for (int i = 0; i < 4; ++i) st[i] = ((const float4*)s)[i];
        }
#pragma unroll
        for (int k8 = 0; k8 < 8; ++k8) {
          const int nk = (k8g + 1 < nk8) ? (k8g + 1) : (nk8 - 1);
          const float4* s = (const float4*)(wpg + (size_t)nk * 64);
#pragma unroll
          for (int i = 0; i < 16; ++i) wnxt[i] = s[i];
          const float4 a0 = *(const float4*)&At[lane * APF + k8 * 8];
          const float4 a1 = *(const float4*)&At[lane * APF + k8 * 8 + 4];
#pragma unroll
          for (int c = 0; c < 8; ++c) {
            const float4 wA = wcur[c];
            const float4 wB = wcur[8 + c];
            acc[c] = fmaf(a0.x, wA.x, acc[c]);
            acc[c] = fmaf(a0.y, wA.y, acc[c]);
            acc[c] = fmaf(a0.z, wA.z, acc[c]);
            acc[c] = fmaf(a0.w, wA.w, acc[c]);
            acc[c] = fmaf(a1.x, wB.x, acc[c]);
            acc[c] = fmaf(a1.y, wB.y, acc[c]);
            acc[c] = fmaf(a1.z, wB.z, acc[c]);
            acc[c] = fmaf(a1.w, wB.w, acc[c]);
          }
#pragma unroll
          for (int i = 0; i < 16; ++i) wcur[i] = wnxt[i];
          ++k8g;
        }
      }
      float* hout = (role ? h1buf : h0buf) + (size_t)wrbuf * BB * HH;
      float2 hv;
#pragma unroll
      for (int cl = 0; cl < 2; ++cl) {
        const float iv = acc[cl * 4 + 0] + bg[cl * 4 + 0];
        const float fv = acc[cl * 4 + 1] + bg[cl * 4 + 1];
        const float gv = acc[cl * 4 + 2] + bg[cl * 4 + 2];
        const float ov = acc[cl * 4 + 3] + bg[cl * 4 + 3];
        const float cn = sig_(fv) * cst[cl] + sig_(iv) * tanhf(gv);
        cst[cl] = cn;
        const float hnv = sig_(ov) * tanhf(cn);
        if (cl == 0) hv.x = hnv; else hv.y = hnv;
      }
      *(float2*)&hout[(size_t)(m0 + srow * 0 + lane) * HH + g8 * 2] = hv;
    }
    __threadfence();
    grid.sync();
  }
}

// ---------------- head ----------------
__global__ __launch_bounds__(256) void head_kernel(const float* __restrict__ h1,
                                                   const float* __restrict__ fc1w,
                                                   const float* __restrict__ fc1b,
                                                   const float* __restrict__ fc2w,
                                                   const float* __restrict__ fc2b,
                                                   float* __restrict__ out) {
  __shared__ float part[256];
  __shared__ float hid[32];
  const int r = blockIdx.x;
  const int tid = threadIdx.x;
  const int c = tid & 31, pt = tid >> 5;
  const float4* ha = (const float4*)(h1 + (size_t)r * HH + pt * 64);
  const float4* wa = (const float4*)(fc1w + (size_t)c * HH + pt * 64);
  float s = 0.f;
#pragma unroll
  for (int j = 0; j < 16; ++j) {
    float4 av = ha[j], wv = wa[j];
    s = fmaf(av.x, wv.x, s);
    s = fmaf(av.y, wv.y, s);
    s = fmaf(av.z, wv.z, s);
    s = fmaf(av.w, wv.w, s);
  }
  part[tid] = s;
  __syncthreads();
  if (tid < 32) {
    float v = fc1b[tid];
#pragma unroll
    for (int q = 0; q < 8; ++q) v += part[q * 32 + tid];
    hid[tid] = fmaxf(v, 0.f);
  }
  __syncthreads();
  if (tid == 0) {
    float v = fc2b[0];
    for (int cc = 0; cc < 32; ++cc) v = fmaf(hid[cc], fc2w[cc], v);
    out[r] = v;
  }
}

extern "C" void kernel_launch(void* const* d_in, const int* in_sizes, int n_in,
                              void* d_out, int out_size, void* d_ws, size_t ws_size,
                              hipStream_t stream) {
  const float* x    = (const float*)d_in[0];
  const float* pw   = (const float*)d_in[1];
  const float* pb   = (const float*)d_in[2];
  const float* wx0  = (const float*)d_in[3];
  const float* bx0  = (const float*)d_in[4];
  const float* wh0  = (const float*)d_in[5];
  const float* bh0  = (const float*)d_in[6];
  const float* wx1  = (const float*)d_in[7];
  const float* bx1  = (const float*)d_in[8];
  const float* wh1  = (const float*)d_in[9];
  const float* bh1  = (const float*)d_in[10];
  const float* fc1w = (const float*)d_in[11];
  const float* fc1b = (const float*)d_in[12];
  const float* fc2w = (const float*)d_in[13];
  const float* fc2b = (const float*)d_in[14];
  float* out = (float*)d_out;

  float* xp = (float*)d_ws;
  float* h0buf = xp + (size_t)BB * TT * DD;
  float* h1buf = h0buf + 2 * BB * HH;
  float* wp0 = h1buf + 2 * BB * HH;
  float* wp1 = wp0 + WP0_FLOATS;

  proj_kernel<<<dim3(4096), dim3(256), 0, stream>>>(x, pw, pb, xp);
  pack_w_kernel<<<dim3((WP1_FLOATS + 255) / 256), dim3(256), 0, stream>>>(
      wx0, wh0, wx1, wh1, wp0, wp1);

  void* kargs[] = {(void*)&xp,  (void*)&wp0, (void*)&wp1, (void*)&bx0,
                   (void*)&bh0, (void*)&bx1, (void*)&bh1, (void*)&h0buf,
                   (void*)&h1buf};
  hipError_t err = hipLaunchCooperativeKernel((void*)lstm512_kernel, dim3(512),
                                              dim3(256), kargs, 0, stream);
  if (err != hipSuccess) {
    (void)hipGetLastError();
    hipLaunchCooperativeKernel((void*)lstm_fb_kernel, dim3(256), dim3(256),
                               kargs, 0, stream);
  }

  head_kernel<<<dim3(BB), dim3(256), 0, stream>>>(h1buf, fc1w, fc1b, fc2w, fc2b, out);
}